// Round 20
// baseline (802.230 us; speedup 1.0000x reference)
//
#include <hip/hip_runtime.h>

// HGTPolicy — round 20: attnagg rel tables moved from LDS to per-lane REGISTERS
// (128 floats for this lane's fixed (h,ee) across all 8 edge types), selected by
// a wave-uniform switch on et. Zero ds_read in the edge loop. Rest = round 19.

#define KT 32   // nodes per kqv tile
#define OT 64   // nodes per out tile

// ---------------- zero fill: two regions ----------------
__global__ void k_zero2(unsigned int* __restrict__ a, int na,
                        unsigned int* __restrict__ b, int nb) {
    int i = blockIdx.x * 256 + threadIdx.x;
    int st = gridDim.x * 256;
    int tot = na + nb;
    for (; i < tot; i += st) {
        if (i < na) a[i] = 0u; else b[i - na] = 0u;
    }
}

// ------- merged: edge flatten + dst histogram (blocks < fb) | embed (rest) -------
__global__ void k_build(const int* __restrict__ p0, const int* __restrict__ p1,
                        const int* __restrict__ p2, const int* __restrict__ p3,
                        const int* __restrict__ p4, const int* __restrict__ p5,
                        const int* __restrict__ p6, const int* __restrict__ p7,
                        int c1, int c2, int c3, int c4, int c5, int c6, int c7, int c8,
                        int* __restrict__ gdst, int* __restrict__ pack,
                        int* __restrict__ cnt, int fb,
                        const float* __restrict__ op_x, const float* __restrict__ mach_x,
                        const float* __restrict__ job_x,
                        const float* __restrict__ W_op, const float* __restrict__ b_op,
                        const float* __restrict__ W_mach, const float* __restrict__ b_mach,
                        const float* __restrict__ W_job, const float* __restrict__ b_job,
                        float* __restrict__ X, float* __restrict__ nacc,
                        int N0, int N1, int N2) {
    if (blockIdx.x < fb) {
        int g = blockIdx.x * 256 + threadIdx.x;
        if (g >= c8) return;
        const int* ep; int base, E0, et, soff, doff;
        int OJ = N0 + N1;
        if (g < c1)      { ep = p0; base = 0;  E0 = c1 - 0;  et = 0; soff = OJ;  doff = 0;  }
        else if (g < c2) { ep = p1; base = c1; E0 = c2 - c1; et = 1; soff = 0;   doff = OJ; }
        else if (g < c3) { ep = p2; base = c2; E0 = c3 - c2; et = 2; soff = 0;   doff = 0;  }
        else if (g < c4) { ep = p3; base = c3; E0 = c4 - c3; et = 3; soff = 0;   doff = 0;  }
        else if (g < c5) { ep = p4; base = c4; E0 = c5 - c4; et = 4; soff = 0;   doff = N0; }
        else if (g < c6) { ep = p5; base = c5; E0 = c6 - c5; et = 5; soff = 0;   doff = N0; }
        else if (g < c7) { ep = p6; base = c6; E0 = c7 - c6; et = 6; soff = N0;  doff = 0;  }
        else             { ep = p7; base = c7; E0 = c8 - c7; et = 7; soff = N0;  doff = 0;  }
        int i = g - base;
        int gd = ep[E0 + i] + doff;
        gdst[g] = gd;
        pack[g] = (ep[i] + soff) | (et << 24);
        atomicAdd(&cnt[gd], 1);
        return;
    }
    // ---- embed all types + per-type moments ----
    int bid = blockIdx.x - fb;        // 0..511
    int tid = threadIdx.x;            // 256 = 4 waves
    int j = tid & 63, w = tid >> 6;
    float w0[8], w1[7], w2[7];
    for (int k = 0; k < 8; k++) w0[k] = W_op[k * 64 + j];
    for (int k = 0; k < 7; k++) w1[k] = W_mach[k * 64 + j];
    for (int k = 0; k < 7; k++) w2[k] = W_job[k * 64 + j];
    float b0 = b_op[j], b1 = b_mach[j], b2 = b_job[j];
    float s10 = 0, s20 = 0, s11 = 0, s21 = 0, s12 = 0, s22 = 0;
    int Ntot = N0 + N1 + N2;
    for (int n = bid * 4 + w; n < Ntot; n += 512 * 4) {
        float a;
        if (n < N0) {
            const float* xr = op_x + (size_t)n * 8;
            a = b0;
            for (int k = 0; k < 8; k++) a += xr[k] * w0[k];
            s10 += a; s20 += a * a;
        } else if (n < N0 + N1) {
            const float* xr = mach_x + (size_t)(n - N0) * 7;
            a = b1;
            for (int k = 0; k < 7; k++) a += xr[k] * w1[k];
            s11 += a; s21 += a * a;
        } else {
            const float* xr = job_x + (size_t)(n - N0 - N1) * 7;
            a = b2;
            for (int k = 0; k < 7; k++) a += xr[k] * w2[k];
            s12 += a; s22 += a * a;
        }
        X[(size_t)n * 64 + j] = a;
    }
    for (int o = 32; o > 0; o >>= 1) {
        s10 += __shfl_down(s10, o); s20 += __shfl_down(s20, o);
        s11 += __shfl_down(s11, o); s21 += __shfl_down(s21, o);
        s12 += __shfl_down(s12, o); s22 += __shfl_down(s22, o);
    }
    __shared__ float r[4][6];
    if (j == 0) {
        r[w][0] = s10; r[w][1] = s20; r[w][2] = s11;
        r[w][3] = s21; r[w][4] = s12; r[w][5] = s22;
    }
    __syncthreads();
    if (tid < 6) {
        float v = r[0][tid] + r[1][tid] + r[2][tid] + r[3][tid];
        atomicAdd(&nacc[tid], v);
    }
}

// ---------------- two-stage wide scan over Ntot keys ----------------
__global__ void k_scan1(const int* __restrict__ cnt, int* __restrict__ partial, int M) {
    __shared__ int s[256];
    int t = threadIdx.x;
    int i = blockIdx.x * 256 + t;
    s[t] = (i < M) ? cnt[i] : 0;
    __syncthreads();
    for (int o = 128; o > 0; o >>= 1) {
        if (t < o) s[t] += s[t + o];
        __syncthreads();
    }
    if (t == 0) partial[blockIdx.x] = s[0];
}

__global__ void k_scan2(const int* __restrict__ cnt, const int* __restrict__ partial,
                        int* __restrict__ rowptr, int* __restrict__ cursor,
                        int M, int Etot) {
    __shared__ int s[256];
    __shared__ int pbase;
    int t = threadIdx.x;
    int ps = 0;
    for (int c = t; c < blockIdx.x; c += 256) ps += partial[c];
    s[t] = ps;
    __syncthreads();
    for (int o = 128; o > 0; o >>= 1) {
        if (t < o) s[t] += s[t + o];
        __syncthreads();
    }
    if (t == 0) pbase = s[0];
    __syncthreads();
    int base = pbase;
    int i = blockIdx.x * 256 + t;
    int v = (i < M) ? cnt[i] : 0;
    s[t] = v;
    __syncthreads();
    for (int off = 1; off < 256; off <<= 1) {
        int add = (t >= off) ? s[t - off] : 0;
        __syncthreads();
        s[t] += add;
        __syncthreads();
    }
    if (i < M) {
        int r = base + s[t] - v;   // exclusive prefix
        rowptr[i] = r;
        cursor[i] = r;
    }
    if (blockIdx.x == 0 && t == 0) rowptr[M] = Etot;
}

// ---- merged: scatter (blocks < sb) | layer-0 KQV+graphnorm (rest), 192 thr ----
__global__ void k_scatkqv(const int* __restrict__ gdst, const int* __restrict__ pack,
                          int* __restrict__ cursor, int* __restrict__ csr, int Etot, int sb,
                          float* __restrict__ X, const float* __restrict__ nacc,
                          const float* __restrict__ ln_gamma, const float* __restrict__ ln_beta,
                          const float* __restrict__ Wl, const float* __restrict__ bl,
                          float* __restrict__ KQV, int tb0, int tb1,
                          int N0, int N1, int N2) {
    __shared__ float Ws[64 * 192];      // 48 KB
    __shared__ float Xs[64 * 36];
    __shared__ float Bs[192];
    if (blockIdx.x < sb) {
        int i = blockIdx.x * 192 + threadIdx.x;
        if (i >= Etot) return;
        int d = gdst[i];
        int pos = atomicAdd(&cursor[d], 1);
        csr[pos] = pack[i];
        return;
    }
    int b = blockIdx.x - sb;
    int t, nbase, Nt, chunk;
    if (b < tb0)            { t = 0; chunk = b;             nbase = 0;       Nt = N0; }
    else if (b < tb0 + tb1) { t = 1; chunk = b - tb0;       nbase = N0;      Nt = N1; }
    else                    { t = 2; chunk = b - tb0 - tb1; nbase = N0 + N1; Nt = N2; }
    int n0 = nbase + chunk * KT;
    int cntm = nbase + Nt - n0; if (cntm > KT) cntm = KT;

    int tid = threadIdx.x;  // 192
    const float* W = Wl + (size_t)t * 64 * 192;
    for (int i = tid; i < 64 * 192; i += 192) Ws[i] = W[i];
    Bs[tid] = bl[t * 192 + tid];

    float inv = 1.0f / ((float)Nt * 64.0f);
    float mu = nacc[2 * t] * inv;
    float var = nacc[2 * t + 1] * inv - mu * mu;
    float sc = 1.0f / (sqrtf(fmaxf(var, 0.0f)) + 1e-5f);
    for (int idx = tid; idx < KT * 64; idx += 192) {
        int m = idx >> 6, k = idx & 63;
        float v = 0.0f;
        if (m < cntm) {
            v = X[(size_t)(n0 + m) * 64 + k];
            v = (v - mu) * sc * ln_gamma[t * 64 + k] + ln_beta[t * 64 + k];
            X[(size_t)(n0 + m) * 64 + k] = v;
        }
        Xs[k * 36 + m] = v;
    }
    __syncthreads();

    int c = tid;
    float bc = Bs[c];
    float acc[KT];
#pragma unroll
    for (int m = 0; m < KT; m++) acc[m] = bc;
    for (int k = 0; k < 64; k++) {
        float wv = Ws[k * 192 + c];
        const float4* xr = (const float4*)(Xs + k * 36);
#pragma unroll
        for (int q = 0; q < KT / 4; q++) {
            float4 x4 = xr[q];
            acc[q * 4 + 0] += x4.x * wv;
            acc[q * 4 + 1] += x4.y * wv;
            acc[q * 4 + 2] += x4.z * wv;
            acc[q * 4 + 3] += x4.w * wv;
        }
    }
    for (int m = 0; m < cntm; m++)
        KQV[(size_t)(n0 + m) * 192 + c] = acc[m];
}

// ---------------- KQV projection (layer >= 1, no norm), 192 threads -------------
__global__ void k_kqvT(const float* __restrict__ X,
                       const float* __restrict__ Wl, const float* __restrict__ bl,
                       float* __restrict__ KQV, int tb0, int tb1,
                       int N0, int N1, int N2) {
    __shared__ float Ws[64 * 192];
    __shared__ float Xs[64 * 36];
    __shared__ float Bs[192];
    int b = blockIdx.x;
    int t, nbase, Nt, chunk;
    if (b < tb0)            { t = 0; chunk = b;             nbase = 0;       Nt = N0; }
    else if (b < tb0 + tb1) { t = 1; chunk = b - tb0;       nbase = N0;      Nt = N1; }
    else                    { t = 2; chunk = b - tb0 - tb1; nbase = N0 + N1; Nt = N2; }
    int n0 = nbase + chunk * KT;
    int cntm = nbase + Nt - n0; if (cntm > KT) cntm = KT;

    int tid = threadIdx.x;  // 192
    const float* W = Wl + (size_t)t * 64 * 192;
    for (int i = tid; i < 64 * 192; i += 192) Ws[i] = W[i];
    Bs[tid] = bl[t * 192 + tid];
    for (int idx = tid; idx < KT * 64; idx += 192) {
        int m = idx >> 6, k = idx & 63;
        Xs[k * 36 + m] = (m < cntm) ? X[(size_t)(n0 + m) * 64 + k] : 0.0f;
    }
    __syncthreads();

    int c = tid;
    float bc = Bs[c];
    float acc[KT];
#pragma unroll
    for (int m = 0; m < KT; m++) acc[m] = bc;
    for (int k = 0; k < 64; k++) {
        float wv = Ws[k * 192 + c];
        const float4* xr = (const float4*)(Xs + k * 36);
#pragma unroll
        for (int q = 0; q < KT / 4; q++) {
            float4 x4 = xr[q];
            acc[q * 4 + 0] += x4.x * wv;
            acc[q * 4 + 1] += x4.y * wv;
            acc[q * 4 + 2] += x4.z * wv;
            acc[q * 4 + 3] += x4.w * wv;
        }
    }
    for (int m = 0; m < cntm; m++)
        KQV[(size_t)(n0 + m) * 192 + c] = acc[m];
}

// per-edge dot with register-resident rel rows; et is wave-uniform -> s_cbranch
__device__ __forceinline__ void edot(int et, const float (&kr)[64], const float (&vr)[64],
                                     float4 k0, float4 k1, float4 v0, float4 v1,
                                     float& ke, float& ve) {
    switch (et) {
#define EDC(ET) case ET: \
        ke = k0.x * kr[ET*8+0] + k0.y * kr[ET*8+1] + k0.z * kr[ET*8+2] + k0.w * kr[ET*8+3] \
           + k1.x * kr[ET*8+4] + k1.y * kr[ET*8+5] + k1.z * kr[ET*8+6] + k1.w * kr[ET*8+7]; \
        ve = v0.x * vr[ET*8+0] + v0.y * vr[ET*8+1] + v0.z * vr[ET*8+2] + v0.w * vr[ET*8+3] \
           + v1.x * vr[ET*8+4] + v1.y * vr[ET*8+5] + v1.z * vr[ET*8+6] + v1.w * vr[ET*8+7]; \
        break;
    EDC(0) EDC(1) EDC(2) EDC(3) EDC(4) EDC(5) EDC(6) EDC(7)
#undef EDC
    default: ke = 0.0f; ve = 0.0f; break;
    }
}

// ------ fused attention + aggregation: register rel tables, no LDS reads --------
__global__ __launch_bounds__(256, 2)
void k_attnagg(const float* __restrict__ KQV, const int* __restrict__ csr,
               const int* __restrict__ rowptr,
               const float* __restrict__ krel_l, const float* __restrict__ vrel_l,
               const float* __restrict__ prel_l, float* __restrict__ agg, int Ntot) {
    int tid = threadIdx.x;   // 256 = 4 waves
    int j = tid & 63, h = j >> 3, ee = j & 7;

    // preload this lane's (h,ee) rel rows for all 8 edge types: 128 VGPRs
    float kr[64], vr[64];
#pragma unroll
    for (int et = 0; et < 8; et++) {
        float ps = prel_l[et * 8 + h] * 0.35355339059327373f;
#pragma unroll
        for (int d = 0; d < 8; d++) {
            kr[et * 8 + d] = krel_l[et * 512 + h * 64 + d * 8 + ee] * ps;
            vr[et * 8 + d] = vrel_l[et * 512 + h * 64 + d * 8 + ee];
        }
    }

    int wave  = blockIdx.x * 4 + (tid >> 6);
    int nwave = gridDim.x * 4;
    for (int n = wave; n < Ntot; n += nwave) {
        float qv = KQV[(size_t)n * 192 + 64 + j];
        float num = 0.0f, den = 0.0f;
        int e0 = rowptr[n], e1 = rowptr[n + 1];
        int idx = e0;
        for (; idx + 2 <= e1; idx += 2) {
            int pk0 = csr[idx], pk1 = csr[idx + 1];
            int sn0 = pk0 & 0xFFFFFF, et0 = ((unsigned int)pk0) >> 24;
            int sn1 = pk1 & 0xFFFFFF, et1 = ((unsigned int)pk1) >> 24;
            const float4* ka = (const float4*)(KQV + (size_t)sn0 * 192 + h * 8);
            const float4* va = (const float4*)(KQV + (size_t)sn0 * 192 + 128 + h * 8);
            const float4* kb = (const float4*)(KQV + (size_t)sn1 * 192 + h * 8);
            const float4* vb = (const float4*)(KQV + (size_t)sn1 * 192 + 128 + h * 8);
            float4 a0 = ka[0], a1 = ka[1], av0 = va[0], av1 = va[1];
            float4 b0 = kb[0], b1 = kb[1], bv0 = vb[0], bv1 = vb[1];
            float ke0, ve0, ke1, ve1;
            edot(et0, kr, vr, a0, a1, av0, av1, ke0, ve0);
            edot(et1, kr, vr, b0, b1, bv0, bv1, ke1, ve1);
            float t0 = qv * ke0;
            t0 += __shfl_xor(t0, 1); t0 += __shfl_xor(t0, 2); t0 += __shfl_xor(t0, 4);
            float t1 = qv * ke1;
            t1 += __shfl_xor(t1, 1); t1 += __shfl_xor(t1, 2); t1 += __shfl_xor(t1, 4);
            float ex0 = __expf(t0);
            float ex1 = __expf(t1);
            num += ex0 * ve0 + ex1 * ve1;
            den += ex0 + ex1;
        }
        if (idx < e1) {
            int pk = csr[idx];
            int sn = pk & 0xFFFFFF, et = ((unsigned int)pk) >> 24;
            const float4* kp = (const float4*)(KQV + (size_t)sn * 192 + h * 8);
            const float4* vp = (const float4*)(KQV + (size_t)sn * 192 + 128 + h * 8);
            float4 k0 = kp[0], k1 = kp[1], v0 = vp[0], v1 = vp[1];
            float ke, ve;
            edot(et, kr, vr, k0, k1, v0, v1, ke, ve);
            float tq = qv * ke;
            tq += __shfl_xor(tq, 1); tq += __shfl_xor(tq, 2); tq += __shfl_xor(tq, 4);
            float ex = __expf(tq);
            num += ex * ve;
            den += ex;
        }
        agg[(size_t)n * 64 + j] = (den > 0.0f) ? (num / den) : 0.0f;
    }
}

// --------- out-projection + gelu + skip, LDS-tiled weights (256 threads) --------
__global__ void k_outT(const float* __restrict__ agg, float* __restrict__ X,
                       const float* __restrict__ Wl, const float* __restrict__ bl,
                       const float* __restrict__ skipl, float* __restrict__ gsum,
                       int tb0, int tb1, int N0, int N1, int N2, int do_pool) {
    __shared__ float Ws[64 * 64];       // 16 KB
    __shared__ float Gs[64 * 68];       // [k][m], row stride 68
    int b = blockIdx.x;
    int t, nbase, Nt, chunk;
    if (b < tb0)            { t = 0; chunk = b;             nbase = 0;       Nt = N0; }
    else if (b < tb0 + tb1) { t = 1; chunk = b - tb0;       nbase = N0;      Nt = N1; }
    else                    { t = 2; chunk = b - tb0 - tb1; nbase = N0 + N1; Nt = N2; }
    int n0 = nbase + chunk * OT;
    int cntm = nbase + Nt - n0; if (cntm > OT) cntm = OT;

    int tid = threadIdx.x;  // 256
    const float* W = Wl + (size_t)t * 64 * 64;
    for (int i = tid; i < 4096; i += 256) Ws[i] = W[i];
    for (int idx = tid; idx < OT * 64; idx += 256) {
        int m = idx >> 6, k = idx & 63;
        float v = 0.0f;
        if (m < cntm) {
            float x = agg[(size_t)(n0 + m) * 64 + k];
            v = 0.5f * x * (1.0f + erff(x * 0.70710678118654752f));
        }
        Gs[k * 68 + m] = v;
    }
    __syncthreads();

    int c = tid & 63, w = tid >> 6;
    float bc = bl[t * 64 + c];
    float gk = 1.0f / (1.0f + __expf(-skipl[t]));
    int m0 = w * 16;
    float acc[16];
#pragma unroll
    for (int i = 0; i < 16; i++) acc[i] = bc;
    for (int k = 0; k < 64; k++) {
        float wv = Ws[k * 64 + c];
        const float4* gr = (const float4*)(Gs + k * 68 + m0);
#pragma unroll
        for (int q = 0; q < 4; q++) {
            float4 g4 = gr[q];
            acc[q * 4 + 0] += g4.x * wv;
            acc[q * 4 + 1] += g4.y * wv;
            acc[q * 4 + 2] += g4.z * wv;
            acc[q * 4 + 3] += g4.w * wv;
        }
    }
    float psum = 0.0f;
    for (int i = 0; i < 16; i++) {
        int m = m0 + i;
        if (m < cntm) {
            float xold = X[(size_t)(n0 + m) * 64 + c];
            float xn = gk * acc[i] + (1.0f - gk) * xold;
            X[(size_t)(n0 + m) * 64 + c] = xn;
            psum += xn;
        }
    }
    if (do_pool) {
        __syncthreads();
        Gs[w * 64 + c] = psum;
        __syncthreads();
        if (tid < 64) {
            float tot = Gs[c] + Gs[64 + c] + Gs[128 + c] + Gs[192 + c];
            atomicAdd(&gsum[t * 64 + c], tot);
        }
    }
}

// ---------------- policy head (8 pairs/block, 512 thr) + value head -------------
__global__ void HGTPolicy_53051436040798_kernel(
        const float* __restrict__ X, const float* __restrict__ gsum,
        const int* __restrict__ op_idx, const int* __restrict__ m_idx,
        const float* __restrict__ Wp1, const float* __restrict__ bp1,
        const float* __restrict__ Wp2, const float* __restrict__ bp2,
        const float* __restrict__ Wp3, const float* __restrict__ bp3,
        const float* __restrict__ Wv1, const float* __restrict__ bv1,
        const float* __restrict__ Wv2, const float* __restrict__ bv2,
        float* __restrict__ out, int N0, int N1, int N2, int P, int nb) {
    int tid = threadIdx.x;           // 512
    if (blockIdx.x == nb) {
        __shared__ float g[192];
        __shared__ float h1[64];
        int j = tid;
        if (j < 192) {
            float Nd = (j < 64) ? (float)N0 : ((j < 128) ? (float)N1 : (float)N2);
            g[j] = gsum[j] / Nd;
        }
        __syncthreads();
        if (j < 64) {
            float a = bv1[j];
            for (int k = 0; k < 192; k++) a += g[k] * Wv1[k * 64 + j];
            h1[j] = fmaxf(a, 0.0f);
        }
        __syncthreads();
        if (j == 0) {
            float v = bv2[0];
            for (int k = 0; k < 64; k++) v += h1[k] * Wv2[k];
            out[P] = v;
        }
        return;
    }
    __shared__ float z[8][320];
    __shared__ float h1p[8][64];
    __shared__ float h2p[8][32];
    int pp = tid >> 6, j = tid & 63;
    int p = blockIdx.x * 8 + pp;
    int valid = (p < P);
    if (valid) {
        int on = op_idx[p], mn = m_idx[p];
        z[pp][j]       = X[(size_t)on * 64 + j];
        z[pp][64 + j]  = X[(size_t)(N0 + mn) * 64 + j];
        z[pp][128 + j] = gsum[j] / (float)N0;
        z[pp][192 + j] = gsum[64 + j] / (float)N1;
        z[pp][256 + j] = gsum[128 + j] / (float)N2;
    }
    __syncthreads();
    if (valid) {
        const float* zp = z[pp];
        float a = bp1[j];
        for (int k = 0; k < 320; k++) a += zp[k] * Wp1[k * 64 + j];
        h1p[pp][j] = fmaxf(a, 0.0f);
    }
    __syncthreads();
    if (valid && j < 32) {
        const float* hp = h1p[pp];
        float a2 = bp2[j];
        for (int k = 0; k < 64; k++) a2 += hp[k] * Wp2[k * 32 + j];
        h2p[pp][j] = fmaxf(a2, 0.0f);
    }
    __syncthreads();
    if (valid && j == 0) {
        const float* hp = h2p[pp];
        float lg = bp3[0];
        for (int k = 0; k < 32; k++) lg += hp[k] * Wp3[k];
        out[p] = lg;
    }
}

extern "C" void kernel_launch(void* const* d_in, const int* in_sizes, int n_in,
                              void* d_out, int out_size, void* d_ws, size_t ws_size,
                              hipStream_t stream) {
    const float* op_x      = (const float*)d_in[0];
    const float* machine_x = (const float*)d_in[1];
    const float* job_x     = (const float*)d_in[2];
    const float* W_op   = (const float*)d_in[3];
    const float* b_op   = (const float*)d_in[4];
    const float* W_mach = (const float*)d_in[5];
    const float* b_mach = (const float*)d_in[6];
    const float* W_job  = (const float*)d_in[7];
    const float* b_job  = (const float*)d_in[8];
    const float* ln_gamma = (const float*)d_in[9];
    const float* ln_beta  = (const float*)d_in[10];
    const float* Wkqv = (const float*)d_in[11];
    const float* bkqv = (const float*)d_in[12];
    const float* krel = (const float*)d_in[13];
    const float* vrel = (const float*)d_in[14];
    const float* prel = (const float*)d_in[15];
    const float* Wout = (const float*)d_in[16];
    const float* bout = (const float*)d_in[17];
    const float* skip = (const float*)d_in[18];
    const float* Wp1 = (const float*)d_in[19];
    const float* bp1 = (const float*)d_in[20];
    const float* Wp2 = (const float*)d_in[21];
    const float* bp2 = (const float*)d_in[22];
    const float* Wp3 = (const float*)d_in[23];
    const float* bp3 = (const float*)d_in[24];
    const float* Wv1 = (const float*)d_in[25];
    const float* bv1 = (const float*)d_in[26];
    const float* Wv2 = (const float*)d_in[27];
    const float* bv2 = (const float*)d_in[28];
    const int* op_idx = (const int*)d_in[37];
    const int* m_idx  = (const int*)d_in[38];

    const int NOP = in_sizes[0] / 8;
    const int NM  = in_sizes[1] / 7;
    const int NJ  = in_sizes[2] / 7;
    const int L   = in_sizes[11] / (3 * 64 * 192);
    const int P   = in_sizes[37];
    const int Ntot = NOP + NM + NJ;

    const int* eptr[8];
    int eoff[9];
    eoff[0] = 0;
    for (int e = 0; e < 8; e++) {
        eptr[e] = (const int*)d_in[29 + e];
        eoff[e + 1] = eoff[e] + in_sizes[29 + e] / 2;
    }
    const int Etot = eoff[8];

    // ---- workspace layout ----
    float* ws = (float*)d_ws;
    size_t o = 0;
    float* X    = ws + o; o += (size_t)Ntot * 64;
    float* KQV  = ws + o; o += (size_t)Ntot * 192;
    float* agg  = ws + o; o += (size_t)Ntot * 64;
    float* gsum = ws + o; o += 192;                 // gsum + nacc contiguous (zeroed)
    float* nacc = ws + o; o += 8;
    int* ib     = (int*)(ws + o);
    size_t io = 0;
    int* cnt     = ib + io; io += Ntot;
    int* rowptr  = ib + io; io += Ntot + 1;
    int* cursor  = ib + io; io += Ntot;
    int* partial = ib + io; io += 1024;
    int* gdst    = ib + io; io += Etot;
    int* packs   = ib + io; io += Etot;
    int* csr     = ib + io; io += Etot;

    // projection grids
    const int kb0 = (NOP + KT - 1) / KT, kb1 = (NM + KT - 1) / KT, kb2 = (NJ + KT - 1) / KT;
    const int kgrid = kb0 + kb1 + kb2;
    const int ob0 = (NOP + OT - 1) / OT, ob1 = (NM + OT - 1) / OT, ob2 = (NJ + OT - 1) / OT;
    const int ogrid = ob0 + ob1 + ob2;
    const int nchunks = (Ntot + 255) / 256;
    const int fb = (Etot + 255) / 256;      // flatten blocks
    const int sb = (Etot + 191) / 192;      // scatter blocks (192-thread kernel)

    // 1) zero cnt + (gsum,nacc)
    k_zero2<<<64, 256, 0, stream>>>((unsigned int*)cnt, Ntot, (unsigned int*)gsum, 200);

    // 2) merged edge-flatten + embed
    k_build<<<fb + 512, 256, 0, stream>>>(
        eptr[0], eptr[1], eptr[2], eptr[3], eptr[4], eptr[5], eptr[6], eptr[7],
        eoff[1], eoff[2], eoff[3], eoff[4], eoff[5], eoff[6], eoff[7], eoff[8],
        gdst, packs, cnt, fb,
        op_x, machine_x, job_x, W_op, b_op, W_mach, b_mach, W_job, b_job,
        X, nacc, NOP, NM, NJ);

    // 3-4) scan
    k_scan1<<<nchunks, 256, 0, stream>>>(cnt, partial, Ntot);
    k_scan2<<<nchunks, 256, 0, stream>>>(cnt, partial, rowptr, cursor, Ntot, Etot);

    // 5) merged scatter + layer-0 graphnorm+KQV
    k_scatkqv<<<sb + kgrid, 192, 0, stream>>>(gdst, packs, cursor, csr, Etot, sb,
                                              X, nacc, ln_gamma, ln_beta,
                                              Wkqv, bkqv, KQV, kb0, kb1, NOP, NM, NJ);

    // 6..10) layers
    for (int l = 0; l < L; l++) {
        if (l > 0) {
            k_kqvT<<<kgrid, 192, 0, stream>>>(X,
                                              Wkqv + (size_t)l * 3 * 64 * 192,
                                              bkqv + (size_t)l * 3 * 192,
                                              KQV, kb0, kb1, NOP, NM, NJ);
        }
        k_attnagg<<<2048, 256, 0, stream>>>(KQV, csr, rowptr,
                                            krel + (size_t)l * 4096,
                                            vrel + (size_t)l * 4096,
                                            prel + (size_t)l * 64,
                                            agg, Ntot);
        k_outT<<<ogrid, 256, 0, stream>>>(agg, X,
                                          Wout + (size_t)l * 3 * 64 * 64,
                                          bout + (size_t)l * 3 * 64,
                                          skip + (size_t)l * 3,
                                          gsum, ob0, ob1, NOP, NM, NJ,
                                          (l + 1 == L) ? 1 : 0);
    }

    // 11) policy + value
    const int nbP = (P + 7) / 8;
    HGTPolicy_53051436040798_kernel<<<nbP + 1, 512, 0, stream>>>(
        X, gsum, op_idx, m_idx, Wp1, bp1, Wp2, bp2, Wp3, bp3,
        Wv1, bv1, Wv2, bv2, (float*)d_out, NOP, NM, NJ, P, nbP);
}

// Round 21
// 640.099 us; speedup vs baseline: 1.2533x; 1.2533x over previous
//
#include <hip/hip_runtime.h>

// HGTPolicy — round 21: revert to round 17 verbatim (measured best: 642 us).
// Hybrid attnagg (flat path for op nodes / run-hoisted for machine+job) on the
// type-sorted CSR; merged flat+embed and scatter+layer0-kqv dispatches.

#define KT 32   // nodes per kqv tile
#define OT 64   // nodes per out tile

// ---------------- zero fill: two regions ----------------
__global__ void k_zero2(unsigned int* __restrict__ a, int na,
                        unsigned int* __restrict__ b, int nb) {
    int i = blockIdx.x * 256 + threadIdx.x;
    int st = gridDim.x * 256;
    int tot = na + nb;
    for (; i < tot; i += st) {
        if (i < na) a[i] = 0u; else b[i - na] = 0u;
    }
}

// ------- merged: edge flatten + (dst,et) histogram | embed (rest) -------
__global__ void k_build(const int* __restrict__ p0, const int* __restrict__ p1,
                        const int* __restrict__ p2, const int* __restrict__ p3,
                        const int* __restrict__ p4, const int* __restrict__ p5,
                        const int* __restrict__ p6, const int* __restrict__ p7,
                        int c1, int c2, int c3, int c4, int c5, int c6, int c7, int c8,
                        int* __restrict__ gkey, int* __restrict__ pack,
                        int* __restrict__ cnt, int fb,
                        const float* __restrict__ op_x, const float* __restrict__ mach_x,
                        const float* __restrict__ job_x,
                        const float* __restrict__ W_op, const float* __restrict__ b_op,
                        const float* __restrict__ W_mach, const float* __restrict__ b_mach,
                        const float* __restrict__ W_job, const float* __restrict__ b_job,
                        float* __restrict__ X, float* __restrict__ nacc,
                        int N0, int N1, int N2) {
    if (blockIdx.x < fb) {
        int g = blockIdx.x * 256 + threadIdx.x;
        if (g >= c8) return;
        const int* ep; int base, E0, et, soff, doff;
        int OJ = N0 + N1;
        if (g < c1)      { ep = p0; base = 0;  E0 = c1 - 0;  et = 0; soff = OJ;  doff = 0;  }
        else if (g < c2) { ep = p1; base = c1; E0 = c2 - c1; et = 1; soff = 0;   doff = OJ; }
        else if (g < c3) { ep = p2; base = c2; E0 = c3 - c2; et = 2; soff = 0;   doff = 0;  }
        else if (g < c4) { ep = p3; base = c3; E0 = c4 - c3; et = 3; soff = 0;   doff = 0;  }
        else if (g < c5) { ep = p4; base = c4; E0 = c5 - c4; et = 4; soff = 0;   doff = N0; }
        else if (g < c6) { ep = p5; base = c5; E0 = c6 - c5; et = 5; soff = 0;   doff = N0; }
        else if (g < c7) { ep = p6; base = c6; E0 = c7 - c6; et = 6; soff = N0;  doff = 0;  }
        else             { ep = p7; base = c7; E0 = c8 - c7; et = 7; soff = N0;  doff = 0;  }
        int i = g - base;
        int kd = (ep[E0 + i] + doff) * 8 + et;
        gkey[g] = kd;
        pack[g] = (ep[i] + soff) | (et << 24);   // keep et for the flat path
        atomicAdd(&cnt[kd], 1);
        return;
    }
    // ---- embed all types + per-type moments ----
    int bid = blockIdx.x - fb;        // 0..511
    int tid = threadIdx.x;            // 256 = 4 waves
    int j = tid & 63, w = tid >> 6;
    float w0[8], w1[7], w2[7];
    for (int k = 0; k < 8; k++) w0[k] = W_op[k * 64 + j];
    for (int k = 0; k < 7; k++) w1[k] = W_mach[k * 64 + j];
    for (int k = 0; k < 7; k++) w2[k] = W_job[k * 64 + j];
    float b0 = b_op[j], b1 = b_mach[j], b2 = b_job[j];
    float s10 = 0, s20 = 0, s11 = 0, s21 = 0, s12 = 0, s22 = 0;
    int Ntot = N0 + N1 + N2;
    for (int n = bid * 4 + w; n < Ntot; n += 512 * 4) {
        float a;
        if (n < N0) {
            const float* xr = op_x + (size_t)n * 8;
            a = b0;
            for (int k = 0; k < 8; k++) a += xr[k] * w0[k];
            s10 += a; s20 += a * a;
        } else if (n < N0 + N1) {
            const float* xr = mach_x + (size_t)(n - N0) * 7;
            a = b1;
            for (int k = 0; k < 7; k++) a += xr[k] * w1[k];
            s11 += a; s21 += a * a;
        } else {
            const float* xr = job_x + (size_t)(n - N0 - N1) * 7;
            a = b2;
            for (int k = 0; k < 7; k++) a += xr[k] * w2[k];
            s12 += a; s22 += a * a;
        }
        X[(size_t)n * 64 + j] = a;
    }
    for (int o = 32; o > 0; o >>= 1) {
        s10 += __shfl_down(s10, o); s20 += __shfl_down(s20, o);
        s11 += __shfl_down(s11, o); s21 += __shfl_down(s21, o);
        s12 += __shfl_down(s12, o); s22 += __shfl_down(s22, o);
    }
    __shared__ float r[4][6];
    if (j == 0) {
        r[w][0] = s10; r[w][1] = s20; r[w][2] = s11;
        r[w][3] = s21; r[w][4] = s12; r[w][5] = s22;
    }
    __syncthreads();
    if (tid < 6) {
        float v = r[0][tid] + r[1][tid] + r[2][tid] + r[3][tid];
        atomicAdd(&nacc[tid], v);
    }
}

// ---------------- two-stage wide scan over M = 8*Ntot keys ----------------
__global__ void k_scan1(const int* __restrict__ cnt, int* __restrict__ partial, int M) {
    __shared__ int s[256];
    int t = threadIdx.x;
    int i = blockIdx.x * 256 + t;
    s[t] = (i < M) ? cnt[i] : 0;
    __syncthreads();
    for (int o = 128; o > 0; o >>= 1) {
        if (t < o) s[t] += s[t + o];
        __syncthreads();
    }
    if (t == 0) partial[blockIdx.x] = s[0];
}

__global__ void k_scan2(const int* __restrict__ cnt, const int* __restrict__ partial,
                        int* __restrict__ rowptr8, int* __restrict__ cursor,
                        int M, int Etot) {
    __shared__ int s[256];
    __shared__ int pbase;
    int t = threadIdx.x;
    int ps = 0;
    for (int c = t; c < blockIdx.x; c += 256) ps += partial[c];
    s[t] = ps;
    __syncthreads();
    for (int o = 128; o > 0; o >>= 1) {
        if (t < o) s[t] += s[t + o];
        __syncthreads();
    }
    if (t == 0) pbase = s[0];
    __syncthreads();
    int base = pbase;
    int i = blockIdx.x * 256 + t;
    int v = (i < M) ? cnt[i] : 0;
    s[t] = v;
    __syncthreads();
    for (int off = 1; off < 256; off <<= 1) {
        int add = (t >= off) ? s[t - off] : 0;
        __syncthreads();
        s[t] += add;
        __syncthreads();
    }
    if (i < M) {
        int r = base + s[t] - v;   // exclusive prefix
        rowptr8[i] = r;
        cursor[i] = r;
    }
    if (blockIdx.x == 0 && t == 0) rowptr8[M] = Etot;
}

// ---- merged: scatter (blocks < sb) | layer-0 KQV+graphnorm (rest), 192 thr ----
__global__ void k_scatkqv(const int* __restrict__ gkey, const int* __restrict__ pack,
                          int* __restrict__ cursor, int* __restrict__ csr, int Etot, int sb,
                          float* __restrict__ X, const float* __restrict__ nacc,
                          const float* __restrict__ ln_gamma, const float* __restrict__ ln_beta,
                          const float* __restrict__ Wl, const float* __restrict__ bl,
                          float* __restrict__ KQV, int tb0, int tb1,
                          int N0, int N1, int N2) {
    __shared__ float Ws[64 * 192];      // 48 KB
    __shared__ float Xs[64 * 36];
    __shared__ float Bs[192];
    if (blockIdx.x < sb) {
        int i = blockIdx.x * 192 + threadIdx.x;
        if (i >= Etot) return;
        int d = gkey[i];
        int pos = atomicAdd(&cursor[d], 1);
        csr[pos] = pack[i];
        return;
    }
    int b = blockIdx.x - sb;
    int t, nbase, Nt, chunk;
    if (b < tb0)            { t = 0; chunk = b;             nbase = 0;       Nt = N0; }
    else if (b < tb0 + tb1) { t = 1; chunk = b - tb0;       nbase = N0;      Nt = N1; }
    else                    { t = 2; chunk = b - tb0 - tb1; nbase = N0 + N1; Nt = N2; }
    int n0 = nbase + chunk * KT;
    int cntm = nbase + Nt - n0; if (cntm > KT) cntm = KT;

    int tid = threadIdx.x;  // 192
    const float* W = Wl + (size_t)t * 64 * 192;
    for (int i = tid; i < 64 * 192; i += 192) Ws[i] = W[i];
    Bs[tid] = bl[t * 192 + tid];

    float inv = 1.0f / ((float)Nt * 64.0f);
    float mu = nacc[2 * t] * inv;
    float var = nacc[2 * t + 1] * inv - mu * mu;
    float sc = 1.0f / (sqrtf(fmaxf(var, 0.0f)) + 1e-5f);
    for (int idx = tid; idx < KT * 64; idx += 192) {
        int m = idx >> 6, k = idx & 63;
        float v = 0.0f;
        if (m < cntm) {
            v = X[(size_t)(n0 + m) * 64 + k];
            v = (v - mu) * sc * ln_gamma[t * 64 + k] + ln_beta[t * 64 + k];
            X[(size_t)(n0 + m) * 64 + k] = v;
        }
        Xs[k * 36 + m] = v;
    }
    __syncthreads();

    int c = tid;
    float bc = Bs[c];
    float acc[KT];
#pragma unroll
    for (int m = 0; m < KT; m++) acc[m] = bc;
    for (int k = 0; k < 64; k++) {
        float wv = Ws[k * 192 + c];
        const float4* xr = (const float4*)(Xs + k * 36);
#pragma unroll
        for (int q = 0; q < KT / 4; q++) {
            float4 x4 = xr[q];
            acc[q * 4 + 0] += x4.x * wv;
            acc[q * 4 + 1] += x4.y * wv;
            acc[q * 4 + 2] += x4.z * wv;
            acc[q * 4 + 3] += x4.w * wv;
        }
    }
    for (int m = 0; m < cntm; m++)
        KQV[(size_t)(n0 + m) * 192 + c] = acc[m];
}

// ---------------- KQV projection (layer >= 1, no norm), 192 threads -------------
__global__ void k_kqvT(const float* __restrict__ X,
                       const float* __restrict__ Wl, const float* __restrict__ bl,
                       float* __restrict__ KQV, int tb0, int tb1,
                       int N0, int N1, int N2) {
    __shared__ float Ws[64 * 192];
    __shared__ float Xs[64 * 36];
    __shared__ float Bs[192];
    int b = blockIdx.x;
    int t, nbase, Nt, chunk;
    if (b < tb0)            { t = 0; chunk = b;             nbase = 0;       Nt = N0; }
    else if (b < tb0 + tb1) { t = 1; chunk = b - tb0;       nbase = N0;      Nt = N1; }
    else                    { t = 2; chunk = b - tb0 - tb1; nbase = N0 + N1; Nt = N2; }
    int n0 = nbase + chunk * KT;
    int cntm = nbase + Nt - n0; if (cntm > KT) cntm = KT;

    int tid = threadIdx.x;  // 192
    const float* W = Wl + (size_t)t * 64 * 192;
    for (int i = tid; i < 64 * 192; i += 192) Ws[i] = W[i];
    Bs[tid] = bl[t * 192 + tid];
    for (int idx = tid; idx < KT * 64; idx += 192) {
        int m = idx >> 6, k = idx & 63;
        Xs[k * 36 + m] = (m < cntm) ? X[(size_t)(n0 + m) * 64 + k] : 0.0f;
    }
    __syncthreads();

    int c = tid;
    float bc = Bs[c];
    float acc[KT];
#pragma unroll
    for (int m = 0; m < KT; m++) acc[m] = bc;
    for (int k = 0; k < 64; k++) {
        float wv = Ws[k * 192 + c];
        const float4* xr = (const float4*)(Xs + k * 36);
#pragma unroll
        for (int q = 0; q < KT / 4; q++) {
            float4 x4 = xr[q];
            acc[q * 4 + 0] += x4.x * wv;
            acc[q * 4 + 1] += x4.y * wv;
            acc[q * 4 + 2] += x4.z * wv;
            acc[q * 4 + 3] += x4.w * wv;
        }
    }
    for (int m = 0; m < cntm; m++)
        KQV[(size_t)(n0 + m) * 192 + c] = acc[m];
}

// ---- hybrid fused attention+aggregation: flat path for ops, run path for m/j ----
__global__ void k_attnagg(const float* __restrict__ KQV, const int* __restrict__ csr,
                          const int* __restrict__ rowptr8,
                          const float* __restrict__ krel_l, const float* __restrict__ vrel_l,
                          const float* __restrict__ prel_l, float* __restrict__ agg,
                          int N0, int Ntot) {
    __shared__ float KRs[8 * 8 * 72];   // stride 72 -> only 2-way bank alias (free)
    __shared__ float VRs[8 * 8 * 72];
    int tid = threadIdx.x;   // 512
    for (int i = tid; i < 4096; i += 512) {
        int eth = i >> 6, rest = i & 63;
        KRs[eth * 72 + rest] = krel_l[i] * (prel_l[eth] * 0.35355339059327373f);
        VRs[eth * 72 + rest] = vrel_l[i];
    }
    __syncthreads();

    int j = tid & 63, h = j >> 3, ee = j & 7;
    int wave  = blockIdx.x * 8 + (tid >> 6);
    int nwave = gridDim.x * 8;
    for (int n = wave; n < Ntot; n += nwave) {
        float qv = KQV[(size_t)n * 192 + 64 + j];
        float num = 0.0f, den = 0.0f;
        int base8 = n * 8;
        if (n < N0) {
            // ---- flat path: short mixed-type rows ----
            int e0 = rowptr8[base8], e1 = rowptr8[base8 + 8];
            int idx = e0;
            for (; idx + 2 <= e1; idx += 2) {
                int pk0 = csr[idx], pk1 = csr[idx + 1];
                int sn0 = pk0 & 0xFFFFFF, et0 = ((unsigned int)pk0) >> 24;
                int sn1 = pk1 & 0xFFFFFF, et1 = ((unsigned int)pk1) >> 24;
                const float4* ka = (const float4*)(KQV + (size_t)sn0 * 192 + h * 8);
                const float4* va = (const float4*)(KQV + (size_t)sn0 * 192 + 128 + h * 8);
                const float4* kb = (const float4*)(KQV + (size_t)sn1 * 192 + h * 8);
                const float4* vb = (const float4*)(KQV + (size_t)sn1 * 192 + 128 + h * 8);
                float4 a0 = ka[0], a1 = ka[1], av0 = va[0], av1 = va[1];
                float4 b0 = kb[0], b1 = kb[1], bv0 = vb[0], bv1 = vb[1];
                const float* KR0 = KRs + (et0 * 8 + h) * 72 + ee;
                const float* VR0 = VRs + (et0 * 8 + h) * 72 + ee;
                const float* KR1 = KRs + (et1 * 8 + h) * 72 + ee;
                const float* VR1 = VRs + (et1 * 8 + h) * 72 + ee;
                float ke0 = a0.x * KR0[0]  + a0.y * KR0[8]  + a0.z * KR0[16] + a0.w * KR0[24]
                          + a1.x * KR0[32] + a1.y * KR0[40] + a1.z * KR0[48] + a1.w * KR0[56];
                float ve0 = av0.x * VR0[0]  + av0.y * VR0[8]  + av0.z * VR0[16] + av0.w * VR0[24]
                          + av1.x * VR0[32] + av1.y * VR0[40] + av1.z * VR0[48] + av1.w * VR0[56];
                float ke1 = b0.x * KR1[0]  + b0.y * KR1[8]  + b0.z * KR1[16] + b0.w * KR1[24]
                          + b1.x * KR1[32] + b1.y * KR1[40] + b1.z * KR1[48] + b1.w * KR1[56];
                float ve1 = bv0.x * VR1[0]  + bv0.y * VR1[8]  + bv0.z * VR1[16] + bv0.w * VR1[24]
                          + bv1.x * VR1[32] + bv1.y * VR1[40] + bv1.z * VR1[48] + bv1.w * VR1[56];
                float t0 = qv * ke0;
                t0 += __shfl_xor(t0, 1); t0 += __shfl_xor(t0, 2); t0 += __shfl_xor(t0, 4);
                float t1 = qv * ke1;
                t1 += __shfl_xor(t1, 1); t1 += __shfl_xor(t1, 2); t1 += __shfl_xor(t1, 4);
                float ex0 = __expf(t0);
                float ex1 = __expf(t1);
                num += ex0 * ve0 + ex1 * ve1;
                den += ex0 + ex1;
            }
            if (idx < e1) {
                int pk = csr[idx];
                int sn = pk & 0xFFFFFF, et = ((unsigned int)pk) >> 24;
                const float4* kr4 = (const float4*)(KQV + (size_t)sn * 192 + h * 8);
                const float4* vr4 = (const float4*)(KQV + (size_t)sn * 192 + 128 + h * 8);
                float4 k0 = kr4[0], k1 = kr4[1], v0 = vr4[0], v1 = vr4[1];
                const float* KR = KRs + (et * 8 + h) * 72 + ee;
                const float* VR = VRs + (et * 8 + h) * 72 + ee;
                float ke = k0.x * KR[0]  + k0.y * KR[8]  + k0.z * KR[16] + k0.w * KR[24]
                         + k1.x * KR[32] + k1.y * KR[40] + k1.z * KR[48] + k1.w * KR[56];
                float ve = v0.x * VR[0]  + v0.y * VR[8]  + v0.z * VR[16] + v0.w * VR[24]
                         + v1.x * VR[32] + v1.y * VR[40] + v1.z * VR[48] + v1.w * VR[56];
                float tq = qv * ke;
                tq += __shfl_xor(tq, 1); tq += __shfl_xor(tq, 2); tq += __shfl_xor(tq, 4);
                float ex = __expf(tq);
                num += ex * ve;
                den += ex;
            }
        } else {
            // ---- run path: machine/job nodes, long single-type runs ----
            int e0 = rowptr8[base8];
            for (int et = 0; et < 8; et++) {
                int e1 = rowptr8[base8 + et + 1];
                if (e0 < e1) {
                    const float* KR = KRs + (et * 8 + h) * 72 + ee;
                    const float* VR = VRs + (et * 8 + h) * 72 + ee;
                    float kr0 = KR[0],  kr1 = KR[8],  kr2 = KR[16], kr3 = KR[24];
                    float kr4 = KR[32], kr5 = KR[40], kr6 = KR[48], kr7 = KR[56];
                    float vq0 = VR[0],  vq1 = VR[8],  vq2 = VR[16], vq3 = VR[24];
                    float vq4 = VR[32], vq5 = VR[40], vq6 = VR[48], vq7 = VR[56];
                    int idx = e0;
                    for (; idx + 2 <= e1; idx += 2) {
                        int sn0 = csr[idx] & 0xFFFFFF, sn1 = csr[idx + 1] & 0xFFFFFF;
                        const float4* ka = (const float4*)(KQV + (size_t)sn0 * 192 + h * 8);
                        const float4* va = (const float4*)(KQV + (size_t)sn0 * 192 + 128 + h * 8);
                        const float4* kb = (const float4*)(KQV + (size_t)sn1 * 192 + h * 8);
                        const float4* vb = (const float4*)(KQV + (size_t)sn1 * 192 + 128 + h * 8);
                        float4 a0 = ka[0], a1 = ka[1], av0 = va[0], av1 = va[1];
                        float4 b0 = kb[0], b1 = kb[1], bv0 = vb[0], bv1 = vb[1];
                        float ke0 = a0.x * kr0 + a0.y * kr1 + a0.z * kr2 + a0.w * kr3
                                  + a1.x * kr4 + a1.y * kr5 + a1.z * kr6 + a1.w * kr7;
                        float ve0 = av0.x * vq0 + av0.y * vq1 + av0.z * vq2 + av0.w * vq3
                                  + av1.x * vq4 + av1.y * vq5 + av1.z * vq6 + av1.w * vq7;
                        float ke1 = b0.x * kr0 + b0.y * kr1 + b0.z * kr2 + b0.w * kr3
                                  + b1.x * kr4 + b1.y * kr5 + b1.z * kr6 + b1.w * kr7;
                        float ve1 = bv0.x * vq0 + bv0.y * vq1 + bv0.z * vq2 + bv0.w * vq3
                                  + bv1.x * vq4 + bv1.y * vq5 + bv1.z * vq6 + bv1.w * vq7;
                        float t0 = qv * ke0;
                        t0 += __shfl_xor(t0, 1); t0 += __shfl_xor(t0, 2); t0 += __shfl_xor(t0, 4);
                        float t1 = qv * ke1;
                        t1 += __shfl_xor(t1, 1); t1 += __shfl_xor(t1, 2); t1 += __shfl_xor(t1, 4);
                        float ex0 = __expf(t0);
                        float ex1 = __expf(t1);
                        num += ex0 * ve0 + ex1 * ve1;
                        den += ex0 + ex1;
                    }
                    if (idx < e1) {
                        int sn = csr[idx] & 0xFFFFFF;
                        const float4* kp = (const float4*)(KQV + (size_t)sn * 192 + h * 8);
                        const float4* vp = (const float4*)(KQV + (size_t)sn * 192 + 128 + h * 8);
                        float4 k0 = kp[0], k1 = kp[1], v0 = vp[0], v1 = vp[1];
                        float ke = k0.x * kr0 + k0.y * kr1 + k0.z * kr2 + k0.w * kr3
                                 + k1.x * kr4 + k1.y * kr5 + k1.z * kr6 + k1.w * kr7;
                        float ve = v0.x * vq0 + v0.y * vq1 + v0.z * vq2 + v0.w * vq3
                                 + v1.x * vq4 + v1.y * vq5 + v1.z * vq6 + v1.w * vq7;
                        float tq = qv * ke;
                        tq += __shfl_xor(tq, 1); tq += __shfl_xor(tq, 2); tq += __shfl_xor(tq, 4);
                        float ex = __expf(tq);
                        num += ex * ve;
                        den += ex;
                    }
                }
                e0 = e1;
            }
        }
        agg[(size_t)n * 64 + j] = (den > 0.0f) ? (num / den) : 0.0f;
    }
}

// --------- out-projection + gelu + skip, LDS-tiled weights (256 threads) --------
__global__ void k_outT(const float* __restrict__ agg, float* __restrict__ X,
                       const float* __restrict__ Wl, const float* __restrict__ bl,
                       const float* __restrict__ skipl, float* __restrict__ gsum,
                       int tb0, int tb1, int N0, int N1, int N2, int do_pool) {
    __shared__ float Ws[64 * 64];       // 16 KB
    __shared__ float Gs[64 * 68];       // [k][m], row stride 68
    int b = blockIdx.x;
    int t, nbase, Nt, chunk;
    if (b < tb0)            { t = 0; chunk = b;             nbase = 0;       Nt = N0; }
    else if (b < tb0 + tb1) { t = 1; chunk = b - tb0;       nbase = N0;      Nt = N1; }
    else                    { t = 2; chunk = b - tb0 - tb1; nbase = N0 + N1; Nt = N2; }
    int n0 = nbase + chunk * OT;
    int cntm = nbase + Nt - n0; if (cntm > OT) cntm = OT;

    int tid = threadIdx.x;  // 256
    const float* W = Wl + (size_t)t * 64 * 64;
    for (int i = tid; i < 4096; i += 256) Ws[i] = W[i];
    for (int idx = tid; idx < OT * 64; idx += 256) {
        int m = idx >> 6, k = idx & 63;
        float v = 0.0f;
        if (m < cntm) {
            float x = agg[(size_t)(n0 + m) * 64 + k];
            v = 0.5f * x * (1.0f + erff(x * 0.70710678118654752f));
        }
        Gs[k * 68 + m] = v;
    }
    __syncthreads();

    int c = tid & 63, w = tid >> 6;
    float bc = bl[t * 64 + c];
    float gk = 1.0f / (1.0f + __expf(-skipl[t]));
    int m0 = w * 16;
    float acc[16];
#pragma unroll
    for (int i = 0; i < 16; i++) acc[i] = bc;
    for (int k = 0; k < 64; k++) {
        float wv = Ws[k * 64 + c];
        const float4* gr = (const float4*)(Gs + k * 68 + m0);
#pragma unroll
        for (int q = 0; q < 4; q++) {
            float4 g4 = gr[q];
            acc[q * 4 + 0] += g4.x * wv;
            acc[q * 4 + 1] += g4.y * wv;
            acc[q * 4 + 2] += g4.z * wv;
            acc[q * 4 + 3] += g4.w * wv;
        }
    }
    float psum = 0.0f;
    for (int i = 0; i < 16; i++) {
        int m = m0 + i;
        if (m < cntm) {
            float xold = X[(size_t)(n0 + m) * 64 + c];
            float xn = gk * acc[i] + (1.0f - gk) * xold;
            X[(size_t)(n0 + m) * 64 + c] = xn;
            psum += xn;
        }
    }
    if (do_pool) {
        __syncthreads();
        Gs[w * 64 + c] = psum;
        __syncthreads();
        if (tid < 64) {
            float tot = Gs[c] + Gs[64 + c] + Gs[128 + c] + Gs[192 + c];
            atomicAdd(&gsum[t * 64 + c], tot);
        }
    }
}

// ---------------- policy head (8 pairs/block, 512 thr) + value head -------------
__global__ void HGTPolicy_53051436040798_kernel(
        const float* __restrict__ X, const float* __restrict__ gsum,
        const int* __restrict__ op_idx, const int* __restrict__ m_idx,
        const float* __restrict__ Wp1, const float* __restrict__ bp1,
        const float* __restrict__ Wp2, const float* __restrict__ bp2,
        const float* __restrict__ Wp3, const float* __restrict__ bp3,
        const float* __restrict__ Wv1, const float* __restrict__ bv1,
        const float* __restrict__ Wv2, const float* __restrict__ bv2,
        float* __restrict__ out, int N0, int N1, int N2, int P, int nb) {
    int tid = threadIdx.x;           // 512
    if (blockIdx.x == nb) {
        __shared__ float g[192];
        __shared__ float h1[64];
        int j = tid;
        if (j < 192) {
            float Nd = (j < 64) ? (float)N0 : ((j < 128) ? (float)N1 : (float)N2);
            g[j] = gsum[j] / Nd;
        }
        __syncthreads();
        if (j < 64) {
            float a = bv1[j];
            for (int k = 0; k < 192; k++) a += g[k] * Wv1[k * 64 + j];
            h1[j] = fmaxf(a, 0.0f);
        }
        __syncthreads();
        if (j == 0) {
            float v = bv2[0];
            for (int k = 0; k < 64; k++) v += h1[k] * Wv2[k];
            out[P] = v;
        }
        return;
    }
    __shared__ float z[8][320];
    __shared__ float h1p[8][64];
    __shared__ float h2p[8][32];
    int pp = tid >> 6, j = tid & 63;
    int p = blockIdx.x * 8 + pp;
    int valid = (p < P);
    if (valid) {
        int on = op_idx[p], mn = m_idx[p];
        z[pp][j]       = X[(size_t)on * 64 + j];
        z[pp][64 + j]  = X[(size_t)(N0 + mn) * 64 + j];
        z[pp][128 + j] = gsum[j] / (float)N0;
        z[pp][192 + j] = gsum[64 + j] / (float)N1;
        z[pp][256 + j] = gsum[128 + j] / (float)N2;
    }
    __syncthreads();
    if (valid) {
        const float* zp = z[pp];
        float a = bp1[j];
        for (int k = 0; k < 320; k++) a += zp[k] * Wp1[k * 64 + j];
        h1p[pp][j] = fmaxf(a, 0.0f);
    }
    __syncthreads();
    if (valid && j < 32) {
        const float* hp = h1p[pp];
        float a2 = bp2[j];
        for (int k = 0; k < 64; k++) a2 += hp[k] * Wp2[k * 32 + j];
        h2p[pp][j] = fmaxf(a2, 0.0f);
    }
    __syncthreads();
    if (valid && j == 0) {
        const float* hp = h2p[pp];
        float lg = bp3[0];
        for (int k = 0; k < 32; k++) lg += hp[k] * Wp3[k];
        out[p] = lg;
    }
}

extern "C" void kernel_launch(void* const* d_in, const int* in_sizes, int n_in,
                              void* d_out, int out_size, void* d_ws, size_t ws_size,
                              hipStream_t stream) {
    const float* op_x      = (const float*)d_in[0];
    const float* machine_x = (const float*)d_in[1];
    const float* job_x     = (const float*)d_in[2];
    const float* W_op   = (const float*)d_in[3];
    const float* b_op   = (const float*)d_in[4];
    const float* W_mach = (const float*)d_in[5];
    const float* b_mach = (const float*)d_in[6];
    const float* W_job  = (const float*)d_in[7];
    const float* b_job  = (const float*)d_in[8];
    const float* ln_gamma = (const float*)d_in[9];
    const float* ln_beta  = (const float*)d_in[10];
    const float* Wkqv = (const float*)d_in[11];
    const float* bkqv = (const float*)d_in[12];
    const float* krel = (const float*)d_in[13];
    const float* vrel = (const float*)d_in[14];
    const float* prel = (const float*)d_in[15];
    const float* Wout = (const float*)d_in[16];
    const float* bout = (const float*)d_in[17];
    const float* skip = (const float*)d_in[18];
    const float* Wp1 = (const float*)d_in[19];
    const float* bp1 = (const float*)d_in[20];
    const float* Wp2 = (const float*)d_in[21];
    const float* bp2 = (const float*)d_in[22];
    const float* Wp3 = (const float*)d_in[23];
    const float* bp3 = (const float*)d_in[24];
    const float* Wv1 = (const float*)d_in[25];
    const float* bv1 = (const float*)d_in[26];
    const float* Wv2 = (const float*)d_in[27];
    const float* bv2 = (const float*)d_in[28];
    const int* op_idx = (const int*)d_in[37];
    const int* m_idx  = (const int*)d_in[38];

    const int NOP = in_sizes[0] / 8;
    const int NM  = in_sizes[1] / 7;
    const int NJ  = in_sizes[2] / 7;
    const int L   = in_sizes[11] / (3 * 64 * 192);
    const int P   = in_sizes[37];
    const int Ntot = NOP + NM + NJ;
    const int M = Ntot * 8;             // (dst, et) key space

    const int* eptr[8];
    int eoff[9];
    eoff[0] = 0;
    for (int e = 0; e < 8; e++) {
        eptr[e] = (const int*)d_in[29 + e];
        eoff[e + 1] = eoff[e] + in_sizes[29 + e] / 2;
    }
    const int Etot = eoff[8];

    // ---- workspace layout ----
    float* ws = (float*)d_ws;
    size_t o = 0;
    float* X    = ws + o; o += (size_t)Ntot * 64;
    float* KQV  = ws + o; o += (size_t)Ntot * 192;
    float* agg  = ws + o; o += (size_t)Ntot * 64;
    float* gsum = ws + o; o += 192;                 // gsum + nacc contiguous (zeroed)
    float* nacc = ws + o; o += 8;
    int* ib     = (int*)(ws + o);
    size_t io = 0;
    int* cnt     = ib + io; io += M;
    int* rowptr8 = ib + io; io += M + 1;
    int* cursor  = ib + io; io += M;
    int* partial = ib + io; io += 2048;
    int* gkey    = ib + io; io += Etot;
    int* packs   = ib + io; io += Etot;
    int* csr     = ib + io; io += Etot;

    // projection grids
    const int kb0 = (NOP + KT - 1) / KT, kb1 = (NM + KT - 1) / KT, kb2 = (NJ + KT - 1) / KT;
    const int kgrid = kb0 + kb1 + kb2;
    const int ob0 = (NOP + OT - 1) / OT, ob1 = (NM + OT - 1) / OT, ob2 = (NJ + OT - 1) / OT;
    const int ogrid = ob0 + ob1 + ob2;
    const int nchunks = (M + 255) / 256;
    const int fb = (Etot + 255) / 256;      // flatten blocks
    const int sb = (Etot + 191) / 192;      // scatter blocks (192-thread kernel)

    // 1) zero cnt[M] + (gsum,nacc)
    k_zero2<<<256, 256, 0, stream>>>((unsigned int*)cnt, M, (unsigned int*)gsum, 200);

    // 2) merged edge-flatten + embed
    k_build<<<fb + 512, 256, 0, stream>>>(
        eptr[0], eptr[1], eptr[2], eptr[3], eptr[4], eptr[5], eptr[6], eptr[7],
        eoff[1], eoff[2], eoff[3], eoff[4], eoff[5], eoff[6], eoff[7], eoff[8],
        gkey, packs, cnt, fb,
        op_x, machine_x, job_x, W_op, b_op, W_mach, b_mach, W_job, b_job,
        X, nacc, NOP, NM, NJ);

    // 3-4) scan
    k_scan1<<<nchunks, 256, 0, stream>>>(cnt, partial, M);
    k_scan2<<<nchunks, 256, 0, stream>>>(cnt, partial, rowptr8, cursor, M, Etot);

    // 5) merged scatter + layer-0 graphnorm+KQV
    k_scatkqv<<<sb + kgrid, 192, 0, stream>>>(gkey, packs, cursor, csr, Etot, sb,
                                              X, nacc, ln_gamma, ln_beta,
                                              Wkqv, bkqv, KQV, kb0, kb1, NOP, NM, NJ);

    // 6..10) layers
    for (int l = 0; l < L; l++) {
        if (l > 0) {
            k_kqvT<<<kgrid, 192, 0, stream>>>(X,
                                              Wkqv + (size_t)l * 3 * 64 * 192,
                                              bkqv + (size_t)l * 3 * 192,
                                              KQV, kb0, kb1, NOP, NM, NJ);
        }
        k_attnagg<<<1024, 512, 0, stream>>>(KQV, csr, rowptr8,
                                            krel + (size_t)l * 4096,
                                            vrel + (size_t)l * 4096,
                                            prel + (size_t)l * 64,
                                            agg, NOP, Ntot);
        k_outT<<<ogrid, 256, 0, stream>>>(agg, X,
                                          Wout + (size_t)l * 3 * 64 * 64,
                                          bout + (size_t)l * 3 * 64,
                                          skip + (size_t)l * 3,
                                          gsum, ob0, ob1, NOP, NM, NJ,
                                          (l + 1 == L) ? 1 : 0);
    }

    // 11) policy + value
    const int nbP = (P + 7) / 8;
    HGTPolicy_53051436040798_kernel<<<nbP + 1, 512, 0, stream>>>(
        X, gsum, op_idx, m_idx, Wp1, bp1, Wp2, bp2, Wp3, bp3,
        Wv1, bv1, Wv2, bv2, (float*)d_out, NOP, NM, NJ, P, nbP);
}

// Round 22
// 628.627 us; speedup vs baseline: 1.2762x; 1.0182x over previous
//
#include <hip/hip_runtime.h>

// HGTPolicy — round 22: R21 (640 us) + compact per-node rowptr emitted by scan2 so
// attnagg can use the R15-verbatim body (106 us codegen: rowptr[n]/rowptr[n+1],
// VGPR 40) while scatter keeps the de-contended typed (dst,et) key space.

#define KT 32   // nodes per kqv tile
#define OT 64   // nodes per out tile

// ---------------- zero fill: two regions ----------------
__global__ void k_zero2(unsigned int* __restrict__ a, int na,
                        unsigned int* __restrict__ b, int nb) {
    int i = blockIdx.x * 256 + threadIdx.x;
    int st = gridDim.x * 256;
    int tot = na + nb;
    for (; i < tot; i += st) {
        if (i < na) a[i] = 0u; else b[i - na] = 0u;
    }
}

// ------- merged: edge flatten + (dst,et) histogram | embed (rest) -------
__global__ void k_build(const int* __restrict__ p0, const int* __restrict__ p1,
                        const int* __restrict__ p2, const int* __restrict__ p3,
                        const int* __restrict__ p4, const int* __restrict__ p5,
                        const int* __restrict__ p6, const int* __restrict__ p7,
                        int c1, int c2, int c3, int c4, int c5, int c6, int c7, int c8,
                        int* __restrict__ gkey, int* __restrict__ pack,
                        int* __restrict__ cnt, int fb,
                        const float* __restrict__ op_x, const float* __restrict__ mach_x,
                        const float* __restrict__ job_x,
                        const float* __restrict__ W_op, const float* __restrict__ b_op,
                        const float* __restrict__ W_mach, const float* __restrict__ b_mach,
                        const float* __restrict__ W_job, const float* __restrict__ b_job,
                        float* __restrict__ X, float* __restrict__ nacc,
                        int N0, int N1, int N2) {
    if (blockIdx.x < fb) {
        int g = blockIdx.x * 256 + threadIdx.x;
        if (g >= c8) return;
        const int* ep; int base, E0, et, soff, doff;
        int OJ = N0 + N1;
        if (g < c1)      { ep = p0; base = 0;  E0 = c1 - 0;  et = 0; soff = OJ;  doff = 0;  }
        else if (g < c2) { ep = p1; base = c1; E0 = c2 - c1; et = 1; soff = 0;   doff = OJ; }
        else if (g < c3) { ep = p2; base = c2; E0 = c3 - c2; et = 2; soff = 0;   doff = 0;  }
        else if (g < c4) { ep = p3; base = c3; E0 = c4 - c3; et = 3; soff = 0;   doff = 0;  }
        else if (g < c5) { ep = p4; base = c4; E0 = c5 - c4; et = 4; soff = 0;   doff = N0; }
        else if (g < c6) { ep = p5; base = c5; E0 = c6 - c5; et = 5; soff = 0;   doff = N0; }
        else if (g < c7) { ep = p6; base = c6; E0 = c7 - c6; et = 6; soff = N0;  doff = 0;  }
        else             { ep = p7; base = c7; E0 = c8 - c7; et = 7; soff = N0;  doff = 0;  }
        int i = g - base;
        int kd = (ep[E0 + i] + doff) * 8 + et;
        gkey[g] = kd;
        pack[g] = (ep[i] + soff) | (et << 24);
        atomicAdd(&cnt[kd], 1);
        return;
    }
    // ---- embed all types + per-type moments ----
    int bid = blockIdx.x - fb;        // 0..511
    int tid = threadIdx.x;            // 256 = 4 waves
    int j = tid & 63, w = tid >> 6;
    float w0[8], w1[7], w2[7];
    for (int k = 0; k < 8; k++) w0[k] = W_op[k * 64 + j];
    for (int k = 0; k < 7; k++) w1[k] = W_mach[k * 64 + j];
    for (int k = 0; k < 7; k++) w2[k] = W_job[k * 64 + j];
    float b0 = b_op[j], b1 = b_mach[j], b2 = b_job[j];
    float s10 = 0, s20 = 0, s11 = 0, s21 = 0, s12 = 0, s22 = 0;
    int Ntot = N0 + N1 + N2;
    for (int n = bid * 4 + w; n < Ntot; n += 512 * 4) {
        float a;
        if (n < N0) {
            const float* xr = op_x + (size_t)n * 8;
            a = b0;
            for (int k = 0; k < 8; k++) a += xr[k] * w0[k];
            s10 += a; s20 += a * a;
        } else if (n < N0 + N1) {
            const float* xr = mach_x + (size_t)(n - N0) * 7;
            a = b1;
            for (int k = 0; k < 7; k++) a += xr[k] * w1[k];
            s11 += a; s21 += a * a;
        } else {
            const float* xr = job_x + (size_t)(n - N0 - N1) * 7;
            a = b2;
            for (int k = 0; k < 7; k++) a += xr[k] * w2[k];
            s12 += a; s22 += a * a;
        }
        X[(size_t)n * 64 + j] = a;
    }
    for (int o = 32; o > 0; o >>= 1) {
        s10 += __shfl_down(s10, o); s20 += __shfl_down(s20, o);
        s11 += __shfl_down(s11, o); s21 += __shfl_down(s21, o);
        s12 += __shfl_down(s12, o); s22 += __shfl_down(s22, o);
    }
    __shared__ float r[4][6];
    if (j == 0) {
        r[w][0] = s10; r[w][1] = s20; r[w][2] = s11;
        r[w][3] = s21; r[w][4] = s12; r[w][5] = s22;
    }
    __syncthreads();
    if (tid < 6) {
        float v = r[0][tid] + r[1][tid] + r[2][tid] + r[3][tid];
        atomicAdd(&nacc[tid], v);
    }
}

// ---------------- two-stage wide scan over M = 8*Ntot keys ----------------
__global__ void k_scan1(const int* __restrict__ cnt, int* __restrict__ partial, int M) {
    __shared__ int s[256];
    int t = threadIdx.x;
    int i = blockIdx.x * 256 + t;
    s[t] = (i < M) ? cnt[i] : 0;
    __syncthreads();
    for (int o = 128; o > 0; o >>= 1) {
        if (t < o) s[t] += s[t + o];
        __syncthreads();
    }
    if (t == 0) partial[blockIdx.x] = s[0];
}

// scan2 additionally emits the compact per-node rowptr: rowptrC[n] = rowptr8[8n]
__global__ void k_scan2(const int* __restrict__ cnt, const int* __restrict__ partial,
                        int* __restrict__ rowptrC, int* __restrict__ cursor,
                        int M, int Etot) {
    __shared__ int s[256];
    __shared__ int pbase;
    int t = threadIdx.x;
    int ps = 0;
    for (int c = t; c < blockIdx.x; c += 256) ps += partial[c];
    s[t] = ps;
    __syncthreads();
    for (int o = 128; o > 0; o >>= 1) {
        if (t < o) s[t] += s[t + o];
        __syncthreads();
    }
    if (t == 0) pbase = s[0];
    __syncthreads();
    int base = pbase;
    int i = blockIdx.x * 256 + t;
    int v = (i < M) ? cnt[i] : 0;
    s[t] = v;
    __syncthreads();
    for (int off = 1; off < 256; off <<= 1) {
        int add = (t >= off) ? s[t - off] : 0;
        __syncthreads();
        s[t] += add;
        __syncthreads();
    }
    if (i < M) {
        int r = base + s[t] - v;   // exclusive prefix
        cursor[i] = r;
        if ((i & 7) == 0) rowptrC[i >> 3] = r;   // node-start offset
    }
    if (blockIdx.x == 0 && t == 0) rowptrC[M >> 3] = Etot;
}

// ---- merged: scatter (blocks < sb) | layer-0 KQV+graphnorm (rest), 192 thr ----
__global__ void k_scatkqv(const int* __restrict__ gkey, const int* __restrict__ pack,
                          int* __restrict__ cursor, int* __restrict__ csr, int Etot, int sb,
                          float* __restrict__ X, const float* __restrict__ nacc,
                          const float* __restrict__ ln_gamma, const float* __restrict__ ln_beta,
                          const float* __restrict__ Wl, const float* __restrict__ bl,
                          float* __restrict__ KQV, int tb0, int tb1,
                          int N0, int N1, int N2) {
    __shared__ float Ws[64 * 192];      // 48 KB
    __shared__ float Xs[64 * 36];
    __shared__ float Bs[192];
    if (blockIdx.x < sb) {
        int i = blockIdx.x * 192 + threadIdx.x;
        if (i >= Etot) return;
        int d = gkey[i];
        int pos = atomicAdd(&cursor[d], 1);
        csr[pos] = pack[i];
        return;
    }
    int b = blockIdx.x - sb;
    int t, nbase, Nt, chunk;
    if (b < tb0)            { t = 0; chunk = b;             nbase = 0;       Nt = N0; }
    else if (b < tb0 + tb1) { t = 1; chunk = b - tb0;       nbase = N0;      Nt = N1; }
    else                    { t = 2; chunk = b - tb0 - tb1; nbase = N0 + N1; Nt = N2; }
    int n0 = nbase + chunk * KT;
    int cntm = nbase + Nt - n0; if (cntm > KT) cntm = KT;

    int tid = threadIdx.x;  // 192
    const float* W = Wl + (size_t)t * 64 * 192;
    for (int i = tid; i < 64 * 192; i += 192) Ws[i] = W[i];
    Bs[tid] = bl[t * 192 + tid];

    float inv = 1.0f / ((float)Nt * 64.0f);
    float mu = nacc[2 * t] * inv;
    float var = nacc[2 * t + 1] * inv - mu * mu;
    float sc = 1.0f / (sqrtf(fmaxf(var, 0.0f)) + 1e-5f);
    for (int idx = tid; idx < KT * 64; idx += 192) {
        int m = idx >> 6, k = idx & 63;
        float v = 0.0f;
        if (m < cntm) {
            v = X[(size_t)(n0 + m) * 64 + k];
            v = (v - mu) * sc * ln_gamma[t * 64 + k] + ln_beta[t * 64 + k];
            X[(size_t)(n0 + m) * 64 + k] = v;
        }
        Xs[k * 36 + m] = v;
    }
    __syncthreads();

    int c = tid;
    float bc = Bs[c];
    float acc[KT];
#pragma unroll
    for (int m = 0; m < KT; m++) acc[m] = bc;
    for (int k = 0; k < 64; k++) {
        float wv = Ws[k * 192 + c];
        const float4* xr = (const float4*)(Xs + k * 36);
#pragma unroll
        for (int q = 0; q < KT / 4; q++) {
            float4 x4 = xr[q];
            acc[q * 4 + 0] += x4.x * wv;
            acc[q * 4 + 1] += x4.y * wv;
            acc[q * 4 + 2] += x4.z * wv;
            acc[q * 4 + 3] += x4.w * wv;
        }
    }
    for (int m = 0; m < cntm; m++)
        KQV[(size_t)(n0 + m) * 192 + c] = acc[m];
}

// ---------------- KQV projection (layer >= 1, no norm), 192 threads -------------
__global__ void k_kqvT(const float* __restrict__ X,
                       const float* __restrict__ Wl, const float* __restrict__ bl,
                       float* __restrict__ KQV, int tb0, int tb1,
                       int N0, int N1, int N2) {
    __shared__ float Ws[64 * 192];
    __shared__ float Xs[64 * 36];
    __shared__ float Bs[192];
    int b = blockIdx.x;
    int t, nbase, Nt, chunk;
    if (b < tb0)            { t = 0; chunk = b;             nbase = 0;       Nt = N0; }
    else if (b < tb0 + tb1) { t = 1; chunk = b - tb0;       nbase = N0;      Nt = N1; }
    else                    { t = 2; chunk = b - tb0 - tb1; nbase = N0 + N1; Nt = N2; }
    int n0 = nbase + chunk * KT;
    int cntm = nbase + Nt - n0; if (cntm > KT) cntm = KT;

    int tid = threadIdx.x;  // 192
    const float* W = Wl + (size_t)t * 64 * 192;
    for (int i = tid; i < 64 * 192; i += 192) Ws[i] = W[i];
    Bs[tid] = bl[t * 192 + tid];
    for (int idx = tid; idx < KT * 64; idx += 192) {
        int m = idx >> 6, k = idx & 63;
        Xs[k * 36 + m] = (m < cntm) ? X[(size_t)(n0 + m) * 64 + k] : 0.0f;
    }
    __syncthreads();

    int c = tid;
    float bc = Bs[c];
    float acc[KT];
#pragma unroll
    for (int m = 0; m < KT; m++) acc[m] = bc;
    for (int k = 0; k < 64; k++) {
        float wv = Ws[k * 192 + c];
        const float4* xr = (const float4*)(Xs + k * 36);
#pragma unroll
        for (int q = 0; q < KT / 4; q++) {
            float4 x4 = xr[q];
            acc[q * 4 + 0] += x4.x * wv;
            acc[q * 4 + 1] += x4.y * wv;
            acc[q * 4 + 2] += x4.z * wv;
            acc[q * 4 + 3] += x4.w * wv;
        }
    }
    for (int m = 0; m < cntm; m++)
        KQV[(size_t)(n0 + m) * 192 + c] = acc[m];
}

// -------- fused attention + aggregation (R15 verbatim body: 106 us codegen) -----
__global__ void k_attnagg(const float* __restrict__ KQV, const int* __restrict__ csr,
                          const int* __restrict__ rowptr,
                          const float* __restrict__ krel_l, const float* __restrict__ vrel_l,
                          const float* __restrict__ prel_l, float* __restrict__ agg, int Ntot) {
    __shared__ float KRs[8 * 8 * 72];   // stride 72 -> only 2-way bank alias (free)
    __shared__ float VRs[8 * 8 * 72];
    int tid = threadIdx.x;   // 512
    for (int i = tid; i < 4096; i += 512) {
        int eth = i >> 6, rest = i & 63;
        KRs[eth * 72 + rest] = krel_l[i] * (prel_l[eth] * 0.35355339059327373f);
        VRs[eth * 72 + rest] = vrel_l[i];
    }
    __syncthreads();

    int j = tid & 63, h = j >> 3, ee = j & 7;
    int wave  = blockIdx.x * 8 + (tid >> 6);
    int nwave = gridDim.x * 8;
    for (int n = wave; n < Ntot; n += nwave) {
        float qv = KQV[(size_t)n * 192 + 64 + j];
        float num = 0.0f, den = 0.0f;
        int e0 = rowptr[n], e1 = rowptr[n + 1];
        int idx = e0;
        for (; idx + 2 <= e1; idx += 2) {
            int pk0 = csr[idx], pk1 = csr[idx + 1];
            int sn0 = pk0 & 0xFFFFFF, et0 = ((unsigned int)pk0) >> 24;
            int sn1 = pk1 & 0xFFFFFF, et1 = ((unsigned int)pk1) >> 24;
            const float4* ka = (const float4*)(KQV + (size_t)sn0 * 192 + h * 8);
            const float4* va = (const float4*)(KQV + (size_t)sn0 * 192 + 128 + h * 8);
            const float4* kb = (const float4*)(KQV + (size_t)sn1 * 192 + h * 8);
            const float4* vb = (const float4*)(KQV + (size_t)sn1 * 192 + 128 + h * 8);
            float4 a0 = ka[0], a1 = ka[1], av0 = va[0], av1 = va[1];
            float4 b0 = kb[0], b1 = kb[1], bv0 = vb[0], bv1 = vb[1];
            const float* KR0 = KRs + (et0 * 8 + h) * 72 + ee;
            const float* VR0 = VRs + (et0 * 8 + h) * 72 + ee;
            const float* KR1 = KRs + (et1 * 8 + h) * 72 + ee;
            const float* VR1 = VRs + (et1 * 8 + h) * 72 + ee;
            float ke0 = a0.x * KR0[0]  + a0.y * KR0[8]  + a0.z * KR0[16] + a0.w * KR0[24]
                      + a1.x * KR0[32] + a1.y * KR0[40] + a1.z * KR0[48] + a1.w * KR0[56];
            float ve0 = av0.x * VR0[0]  + av0.y * VR0[8]  + av0.z * VR0[16] + av0.w * VR0[24]
                      + av1.x * VR0[32] + av1.y * VR0[40] + av1.z * VR0[48] + av1.w * VR0[56];
            float ke1 = b0.x * KR1[0]  + b0.y * KR1[8]  + b0.z * KR1[16] + b0.w * KR1[24]
                      + b1.x * KR1[32] + b1.y * KR1[40] + b1.z * KR1[48] + b1.w * KR1[56];
            float ve1 = bv0.x * VR1[0]  + bv0.y * VR1[8]  + bv0.z * VR1[16] + bv0.w * VR1[24]
                      + bv1.x * VR1[32] + bv1.y * VR1[40] + bv1.z * VR1[48] + bv1.w * VR1[56];
            float t0 = qv * ke0;
            t0 += __shfl_xor(t0, 1); t0 += __shfl_xor(t0, 2); t0 += __shfl_xor(t0, 4);
            float t1 = qv * ke1;
            t1 += __shfl_xor(t1, 1); t1 += __shfl_xor(t1, 2); t1 += __shfl_xor(t1, 4);
            float ex0 = __expf(t0);
            float ex1 = __expf(t1);
            num += ex0 * ve0 + ex1 * ve1;
            den += ex0 + ex1;
        }
        if (idx < e1) {
            int pk = csr[idx];
            int sn = pk & 0xFFFFFF, et = ((unsigned int)pk) >> 24;
            const float4* kr4 = (const float4*)(KQV + (size_t)sn * 192 + h * 8);
            const float4* vr4 = (const float4*)(KQV + (size_t)sn * 192 + 128 + h * 8);
            float4 k0 = kr4[0], k1 = kr4[1], v0 = vr4[0], v1 = vr4[1];
            const float* KR = KRs + (et * 8 + h) * 72 + ee;
            const float* VR = VRs + (et * 8 + h) * 72 + ee;
            float ke = k0.x * KR[0]  + k0.y * KR[8]  + k0.z * KR[16] + k0.w * KR[24]
                     + k1.x * KR[32] + k1.y * KR[40] + k1.z * KR[48] + k1.w * KR[56];
            float ve = v0.x * VR[0]  + v0.y * VR[8]  + v0.z * VR[16] + v0.w * VR[24]
                     + v1.x * VR[32] + v1.y * VR[40] + v1.z * VR[48] + v1.w * VR[56];
            float tq = qv * ke;
            tq += __shfl_xor(tq, 1); tq += __shfl_xor(tq, 2); tq += __shfl_xor(tq, 4);
            float ex = __expf(tq);
            num += ex * ve;
            den += ex;
        }
        agg[(size_t)n * 64 + j] = (den > 0.0f) ? (num / den) : 0.0f;
    }
}

// --------- out-projection + gelu + skip, LDS-tiled weights (256 threads) --------
__global__ void k_outT(const float* __restrict__ agg, float* __restrict__ X,
                       const float* __restrict__ Wl, const float* __restrict__ bl,
                       const float* __restrict__ skipl, float* __restrict__ gsum,
                       int tb0, int tb1, int N0, int N1, int N2, int do_pool) {
    __shared__ float Ws[64 * 64];       // 16 KB
    __shared__ float Gs[64 * 68];       // [k][m], row stride 68
    int b = blockIdx.x;
    int t, nbase, Nt, chunk;
    if (b < tb0)            { t = 0; chunk = b;             nbase = 0;       Nt = N0; }
    else if (b < tb0 + tb1) { t = 1; chunk = b - tb0;       nbase = N0;      Nt = N1; }
    else                    { t = 2; chunk = b - tb0 - tb1; nbase = N0 + N1; Nt = N2; }
    int n0 = nbase + chunk * OT;
    int cntm = nbase + Nt - n0; if (cntm > OT) cntm = OT;

    int tid = threadIdx.x;  // 256
    const float* W = Wl + (size_t)t * 64 * 64;
    for (int i = tid; i < 4096; i += 256) Ws[i] = W[i];
    for (int idx = tid; idx < OT * 64; idx += 256) {
        int m = idx >> 6, k = idx & 63;
        float v = 0.0f;
        if (m < cntm) {
            float x = agg[(size_t)(n0 + m) * 64 + k];
            v = 0.5f * x * (1.0f + erff(x * 0.70710678118654752f));
        }
        Gs[k * 68 + m] = v;
    }
    __syncthreads();

    int c = tid & 63, w = tid >> 6;
    float bc = bl[t * 64 + c];
    float gk = 1.0f / (1.0f + __expf(-skipl[t]));
    int m0 = w * 16;
    float acc[16];
#pragma unroll
    for (int i = 0; i < 16; i++) acc[i] = bc;
    for (int k = 0; k < 64; k++) {
        float wv = Ws[k * 64 + c];
        const float4* gr = (const float4*)(Gs + k * 68 + m0);
#pragma unroll
        for (int q = 0; q < 4; q++) {
            float4 g4 = gr[q];
            acc[q * 4 + 0] += g4.x * wv;
            acc[q * 4 + 1] += g4.y * wv;
            acc[q * 4 + 2] += g4.z * wv;
            acc[q * 4 + 3] += g4.w * wv;
        }
    }
    float psum = 0.0f;
    for (int i = 0; i < 16; i++) {
        int m = m0 + i;
        if (m < cntm) {
            float xold = X[(size_t)(n0 + m) * 64 + c];
            float xn = gk * acc[i] + (1.0f - gk) * xold;
            X[(size_t)(n0 + m) * 64 + c] = xn;
            psum += xn;
        }
    }
    if (do_pool) {
        __syncthreads();
        Gs[w * 64 + c] = psum;
        __syncthreads();
        if (tid < 64) {
            float tot = Gs[c] + Gs[64 + c] + Gs[128 + c] + Gs[192 + c];
            atomicAdd(&gsum[t * 64 + c], tot);
        }
    }
}

// ---------------- policy head (8 pairs/block, 512 thr) + value head -------------
__global__ void HGTPolicy_53051436040798_kernel(
        const float* __restrict__ X, const float* __restrict__ gsum,
        const int* __restrict__ op_idx, const int* __restrict__ m_idx,
        const float* __restrict__ Wp1, const float* __restrict__ bp1,
        const float* __restrict__ Wp2, const float* __restrict__ bp2,
        const float* __restrict__ Wp3, const float* __restrict__ bp3,
        const float* __restrict__ Wv1, const float* __restrict__ bv1,
        const float* __restrict__ Wv2, const float* __restrict__ bv2,
        float* __restrict__ out, int N0, int N1, int N2, int P, int nb) {
    int tid = threadIdx.x;           // 512
    if (blockIdx.x == nb) {
        __shared__ float g[192];
        __shared__ float h1[64];
        int j = tid;
        if (j < 192) {
            float Nd = (j < 64) ? (float)N0 : ((j < 128) ? (float)N1 : (float)N2);
            g[j] = gsum[j] / Nd;
        }
        __syncthreads();
        if (j < 64) {
            float a = bv1[j];
            for (int k = 0; k < 192; k++) a += g[k] * Wv1[k * 64 + j];
            h1[j] = fmaxf(a, 0.0f);
        }
        __syncthreads();
        if (j == 0) {
            float v = bv2[0];
            for (int k = 0; k < 64; k++) v += h1[k] * Wv2[k];
            out[P] = v;
        }
        return;
    }
    __shared__ float z[8][320];
    __shared__ float h1p[8][64];
    __shared__ float h2p[8][32];
    int pp = tid >> 6, j = tid & 63;
    int p = blockIdx.x * 8 + pp;
    int valid = (p < P);
    if (valid) {
        int on = op_idx[p], mn = m_idx[p];
        z[pp][j]       = X[(size_t)on * 64 + j];
        z[pp][64 + j]  = X[(size_t)(N0 + mn) * 64 + j];
        z[pp][128 + j] = gsum[j] / (float)N0;
        z[pp][192 + j] = gsum[64 + j] / (float)N1;
        z[pp][256 + j] = gsum[128 + j] / (float)N2;
    }
    __syncthreads();
    if (valid) {
        const float* zp = z[pp];
        float a = bp1[j];
        for (int k = 0; k < 320; k++) a += zp[k] * Wp1[k * 64 + j];
        h1p[pp][j] = fmaxf(a, 0.0f);
    }
    __syncthreads();
    if (valid && j < 32) {
        const float* hp = h1p[pp];
        float a2 = bp2[j];
        for (int k = 0; k < 64; k++) a2 += hp[k] * Wp2[k * 32 + j];
        h2p[pp][j] = fmaxf(a2, 0.0f);
    }
    __syncthreads();
    if (valid && j == 0) {
        const float* hp = h2p[pp];
        float lg = bp3[0];
        for (int k = 0; k < 32; k++) lg += hp[k] * Wp3[k];
        out[p] = lg;
    }
}

extern "C" void kernel_launch(void* const* d_in, const int* in_sizes, int n_in,
                              void* d_out, int out_size, void* d_ws, size_t ws_size,
                              hipStream_t stream) {
    const float* op_x      = (const float*)d_in[0];
    const float* machine_x = (const float*)d_in[1];
    const float* job_x     = (const float*)d_in[2];
    const float* W_op   = (const float*)d_in[3];
    const float* b_op   = (const float*)d_in[4];
    const float* W_mach = (const float*)d_in[5];
    const float* b_mach = (const float*)d_in[6];
    const float* W_job  = (const float*)d_in[7];
    const float* b_job  = (const float*)d_in[8];
    const float* ln_gamma = (const float*)d_in[9];
    const float* ln_beta  = (const float*)d_in[10];
    const float* Wkqv = (const float*)d_in[11];
    const float* bkqv = (const float*)d_in[12];
    const float* krel = (const float*)d_in[13];
    const float* vrel = (const float*)d_in[14];
    const float* prel = (const float*)d_in[15];
    const float* Wout = (const float*)d_in[16];
    const float* bout = (const float*)d_in[17];
    const float* skip = (const float*)d_in[18];
    const float* Wp1 = (const float*)d_in[19];
    const float* bp1 = (const float*)d_in[20];
    const float* Wp2 = (const float*)d_in[21];
    const float* bp2 = (const float*)d_in[22];
    const float* Wp3 = (const float*)d_in[23];
    const float* bp3 = (const float*)d_in[24];
    const float* Wv1 = (const float*)d_in[25];
    const float* bv1 = (const float*)d_in[26];
    const float* Wv2 = (const float*)d_in[27];
    const float* bv2 = (const float*)d_in[28];
    const int* op_idx = (const int*)d_in[37];
    const int* m_idx  = (const int*)d_in[38];

    const int NOP = in_sizes[0] / 8;
    const int NM  = in_sizes[1] / 7;
    const int NJ  = in_sizes[2] / 7;
    const int L   = in_sizes[11] / (3 * 64 * 192);
    const int P   = in_sizes[37];
    const int Ntot = NOP + NM + NJ;
    const int M = Ntot * 8;             // (dst, et) key space

    const int* eptr[8];
    int eoff[9];
    eoff[0] = 0;
    for (int e = 0; e < 8; e++) {
        eptr[e] = (const int*)d_in[29 + e];
        eoff[e + 1] = eoff[e] + in_sizes[29 + e] / 2;
    }
    const int Etot = eoff[8];

    // ---- workspace layout ----
    float* ws = (float*)d_ws;
    size_t o = 0;
    float* X    = ws + o; o += (size_t)Ntot * 64;
    float* KQV  = ws + o; o += (size_t)Ntot * 192;
    float* agg  = ws + o; o += (size_t)Ntot * 64;
    float* gsum = ws + o; o += 192;                 // gsum + nacc contiguous (zeroed)
    float* nacc = ws + o; o += 8;
    int* ib     = (int*)(ws + o);
    size_t io = 0;
    int* cnt     = ib + io; io += M;
    int* rowptrC = ib + io; io += Ntot + 1;         // compact per-node rowptr
    int* cursor  = ib + io; io += M;
    int* partial = ib + io; io += 2048;
    int* gkey    = ib + io; io += Etot;
    int* packs   = ib + io; io += Etot;
    int* csr     = ib + io; io += Etot;

    // projection grids
    const int kb0 = (NOP + KT - 1) / KT, kb1 = (NM + KT - 1) / KT, kb2 = (NJ + KT - 1) / KT;
    const int kgrid = kb0 + kb1 + kb2;
    const int ob0 = (NOP + OT - 1) / OT, ob1 = (NM + OT - 1) / OT, ob2 = (NJ + OT - 1) / OT;
    const int ogrid = ob0 + ob1 + ob2;
    const int nchunks = (M + 255) / 256;
    const int fb = (Etot + 255) / 256;      // flatten blocks
    const int sb = (Etot + 191) / 192;      // scatter blocks (192-thread kernel)

    // 1) zero cnt[M] + (gsum,nacc)
    k_zero2<<<256, 256, 0, stream>>>((unsigned int*)cnt, M, (unsigned int*)gsum, 200);

    // 2) merged edge-flatten + embed
    k_build<<<fb + 512, 256, 0, stream>>>(
        eptr[0], eptr[1], eptr[2], eptr[3], eptr[4], eptr[5], eptr[6], eptr[7],
        eoff[1], eoff[2], eoff[3], eoff[4], eoff[5], eoff[6], eoff[7], eoff[8],
        gkey, packs, cnt, fb,
        op_x, machine_x, job_x, W_op, b_op, W_mach, b_mach, W_job, b_job,
        X, nacc, NOP, NM, NJ);

    // 3-4) scan (emits compact rowptrC alongside cursors)
    k_scan1<<<nchunks, 256, 0, stream>>>(cnt, partial, M);
    k_scan2<<<nchunks, 256, 0, stream>>>(cnt, partial, rowptrC, cursor, M, Etot);

    // 5) merged scatter + layer-0 graphnorm+KQV
    k_scatkqv<<<sb + kgrid, 192, 0, stream>>>(gkey, packs, cursor, csr, Etot, sb,
                                              X, nacc, ln_gamma, ln_beta,
                                              Wkqv, bkqv, KQV, kb0, kb1, NOP, NM, NJ);

    // 6..10) layers
    for (int l = 0; l < L; l++) {
        if (l > 0) {
            k_kqvT<<<kgrid, 192, 0, stream>>>(X,
                                              Wkqv + (size_t)l * 3 * 64 * 192,
                                              bkqv + (size_t)l * 3 * 192,
                                              KQV, kb0, kb1, NOP, NM, NJ);
        }
        k_attnagg<<<1024, 512, 0, stream>>>(KQV, csr, rowptrC,
                                            krel + (size_t)l * 4096,
                                            vrel + (size_t)l * 4096,
                                            prel + (size_t)l * 64,
                                            agg, Ntot);
        k_outT<<<ogrid, 256, 0, stream>>>(agg, X,
                                          Wout + (size_t)l * 3 * 64 * 64,
                                          bout + (size_t)l * 3 * 64,
                                          skip + (size_t)l * 3,
                                          gsum, ob0, ob1, NOP, NM, NJ,
                                          (l + 1 == L) ? 1 : 0);
    }

    // 11) policy + value
    const int nbP = (P + 7) / 8;
    HGTPolicy_53051436040798_kernel<<<nbP + 1, 512, 0, stream>>>(
        X, gsum, op_idx, m_idx, Wp1, bp1, Wp2, bp2, Wp3, bp3,
        Wv1, bv1, Wv2, bv2, (float*)d_out, NOP, NM, NJ, P, nbP);
}